// Round 8
// baseline (249.852 us; speedup 1.0000x reference)
//
#include <hip/hip_runtime.h>
#include <hip/hip_bf16.h>

// out[128,12288] = [ clip(x[:, :6144] @ R, 0, 1) | zeros ]
// M=128, K=N=6144. R (151 MB fp32) streamed ONCE with 1KB-contiguous wave
// reads; fused k-transpose in registers (pk2->bf16) -> swizzled LDS [n][k];
// MFMA 16x16x32; 16 K-chunks (XCD-aligned) -> fp32 partials in FRAGMENT
// ORDER (1KB-contiguous writes); reduce sums 16 chunks, clips, un-permutes
// via LDS, writes out + zero tail.

#define NPIX 12288
#define NV   6144
#define MR   128
#define LDA  6208          // A row pitch (shorts)
#define CH   16            // K chunks
#define KCH  384           // NV/CH
#define KST4 64            // K per pipeline step
#define BN4  256           // N per block
#define NSI4 6             // KCH/KST4
#define REGF 4096          // f32 per (chunk,nb,wave) partial region
#define SLOTF ((size_t)192 * REGF)   // f32 per chunk slot (24 nb x 8 w)

typedef __attribute__((ext_vector_type(8))) short bf16x8;
typedef __attribute__((ext_vector_type(4))) float f32x4;
typedef __attribute__((ext_vector_type(4))) unsigned u32x4;

__device__ __forceinline__ unsigned pk2(float lo, float hi) {
    __hip_bfloat162 h = __float22bfloat162_rn(make_float2(lo, hi));
    union { __hip_bfloat162 h; unsigned u; } v; v.h = h; return v.u;
}

__device__ __forceinline__ int swz(int row) {
    return ((row ^ (row >> 3)) & 7) << 4;
}

// ---- prep: x[:, :6144] fp32 -> bf16 A[128][LDA] ----
__global__ __launch_bounds__(256) void prep_kernel(const float* __restrict__ x,
                                                   unsigned short* __restrict__ abf) {
    int q = blockIdx.x * 256 + threadIdx.x;   // 0 .. 98303
    int m = q / (NV / 8);
    int r = q % (NV / 8);
    int k = r * 8;
    const float* src = x + (size_t)m * NPIX + k;
    f32x4 a = *(const f32x4*)(src);
    f32x4 b = *(const f32x4*)(src + 4);
    u32x4 o;
    o[0] = pk2(a[0], a[1]); o[1] = pk2(a[2], a[3]);
    o[2] = pk2(b[0], b[1]); o[3] = pk2(b[2], b[3]);
    *(u32x4*)(abf + (size_t)m * LDA + k) = o;
}

// ---- gemm4 helpers ----
__device__ __forceinline__ void sload4(const float*& rp, f32x4 (&r)[8]) {
    #pragma unroll
    for (int j = 0; j < 8; ++j) r[j] = *(const f32x4*)(rp + (size_t)j * NV);
    rp += (size_t)KST4 * NV;
}

__device__ __forceinline__ void wstage4(unsigned char* buf, const f32x4 (&r)[8],
                                        int l, int w) {
    #pragma unroll
    for (int c = 0; c < 4; ++c) {
        const int row = l * 4 + c;        // n_loc 0..255
        u32x4 o;
        o[0] = pk2(r[0][c], r[1][c]);
        o[1] = pk2(r[2][c], r[3][c]);
        o[2] = pk2(r[4][c], r[5][c]);
        o[3] = pk2(r[6][c], r[7][c]);
        *(u32x4*)(buf + row * 128 + ((w * 16) ^ swz(row))) = o;
    }
}

__device__ __forceinline__ void compute4(const unsigned char* buf,
        const unsigned short* __restrict__ A, size_t abase,
        int wn, int ln, int lg, f32x4 (&acc)[4][4]) {
    bf16x8 afr[4][2];
    #pragma unroll
    for (int mt = 0; mt < 4; ++mt)
        #pragma unroll
        for (int ks = 0; ks < 2; ++ks)
            afr[mt][ks] = *(const bf16x8*)(A + abase + (size_t)(mt * 16) * LDA + ks * 32);
    #pragma unroll
    for (int nt = 0; nt < 4; ++nt) {
        const int row = wn * 64 + nt * 16 + ln;
        const int sw = swz(row);
        #pragma unroll
        for (int ks = 0; ks < 2; ++ks) {
            bf16x8 bfr = *(const bf16x8*)(buf + row * 128 + (((ks * 4 + lg) * 16) ^ sw));
            #pragma unroll
            for (int mt = 0; mt < 4; ++mt)
                acc[mt][nt] = __builtin_amdgcn_mfma_f32_16x16x32_bf16(afr[mt][ks], bfr, acc[mt][nt], 0, 0, 0);
        }
    }
}

// ---- gemm4: grid 384 = 24 n-stripes x 16 chunks (chunk = bid&15), 512 thr ----
// Per step: tile [64 k][256 n] fp32. Wave w stages k-rows w*8..w*8+7 with
// 1KB-contiguous reads (lane l: f32x4 at n0+l*4), packs k-octets to bf16,
// ds_write_b128 into swizzled [256 n][128 B] LDS. Compute: wave (wm=w>>2,
// wn=w&3) owns [64 m][64 n]; 32 MFMA/step. Partials in fragment order.
__global__ __launch_bounds__(512) void gemm4_kernel(
        const unsigned short* __restrict__ A,
        const float* __restrict__ R,
        float* __restrict__ part) {
    __shared__ __align__(16) unsigned char Bs0[BN4 * 128];  // 32KB
    __shared__ __align__(16) unsigned char Bs1[BN4 * 128];

    const int tid = threadIdx.x;
    const int w = tid >> 6, l = tid & 63;
    const int ln = l & 15, lg = (l >> 4) & 3;
    const int wm = w >> 2, wn = w & 3;
    const int chunk = blockIdx.x & 15;
    const int nb = blockIdx.x >> 4;          // 0..23
    const int n0 = nb * BN4;
    const int kbase = chunk * KCH;

    const float* rp = R + (size_t)(kbase + w * 8) * NV + n0 + l * 4;
    const size_t abase = (size_t)(wm * 64 + ln) * LDA + kbase + lg * 8;

    f32x4 acc[4][4];
    #pragma unroll
    for (int a = 0; a < 4; ++a)
        #pragma unroll
        for (int b = 0; b < 4; ++b) {
            acc[a][b][0] = 0.f; acc[a][b][1] = 0.f;
            acc[a][b][2] = 0.f; acc[a][b][3] = 0.f;
        }

    f32x4 ring0[8], ring1[8];
    sload4(rp, ring0);                  // step 0
    sload4(rp, ring1);                  // step 1
    wstage4(Bs0, ring0, l, w);
    __syncthreads();

    #pragma unroll 1
    for (int it = 0; it < NSI4 / 2; ++it) {
        const int s = it * 2;
        if (s + 2 < NSI4) sload4(rp, ring0);                       // prefetch s+2
        compute4(Bs0, A, abase + (size_t)s * KST4, wn, ln, lg, acc);
        wstage4(Bs1, ring1, l, w);
        __syncthreads();
        if (s + 3 < NSI4) sload4(rp, ring1);                       // prefetch s+3
        compute4(Bs1, A, abase + (size_t)(s + 1) * KST4, wn, ln, lg, acc);
        if (s + 2 < NSI4) wstage4(Bs0, ring0, l, w);
        __syncthreads();
    }

    // fragment-order store: 16 x 1KB-contiguous wave stores
    float* dst = part + ((((size_t)chunk * 24 + nb) * 8 + w) << 12);
    #pragma unroll
    for (int mt = 0; mt < 4; ++mt)
        #pragma unroll
        for (int nt = 0; nt < 4; ++nt)
            *(f32x4*)(dst + ((((mt * 4 + nt) << 6) + l) << 2)) = acc[mt][nt];
}

// ---- reduce4: grid 192 = 24 nb x 8 w, 256 thr. Sum 16 chunks (coalesced
// fragment-order reads), clip, un-permute via LDS, write out + zero tail ----
__global__ __launch_bounds__(256) void reduce4_kernel(float* __restrict__ out,
        const float* __restrict__ part) {
    __shared__ float T[64][68];
    const int t = threadIdx.x;
    const int nb = blockIdx.x >> 3, w = blockIdx.x & 7;
    const int lg = (t >> 4) & 3, ln = t & 15, hi = t >> 6;
    const size_t rbase = (((size_t)nb * 8 + w) << 12);

    #pragma unroll 1
    for (int u = 0; u < 4; ++u) {           // u == mt
        const size_t off = rbase + u * 1024 + t * 4;
        f32x4 s;
        s[0] = 0.f; s[1] = 0.f; s[2] = 0.f; s[3] = 0.f;
        #pragma unroll
        for (int c = 0; c < CH; ++c) {
            const f32x4 v = *(const f32x4*)(part + (size_t)c * SLOTF + off);
            #pragma unroll
            for (int i = 0; i < 4; ++i) s[i] += v[i];
        }
        const int nloc = hi * 16 + ln;      // nt*16 + ln
        #pragma unroll
        for (int j = 0; j < 4; ++j)
            T[u * 16 + lg * 4 + j][nloc] = fminf(fmaxf(s[j], 0.f), 1.f);
    }
    __syncthreads();

    const int r = t >> 2, sq = t & 3;
    const size_t orow = (size_t)((w >> 2) * 64 + r) * NPIX
                      + (size_t)nb * 256 + (w & 3) * 64;
    #pragma unroll
    for (int u = 0; u < 4; ++u) {
        const int col = u * 16 + sq * 4;
        f32x4 v = *(const f32x4*)(&T[r][col]);
        *(f32x4*)(out + orow + col) = v;
        f32x4 z;
        z[0] = 0.f; z[1] = 0.f; z[2] = 0.f; z[3] = 0.f;
        *(f32x4*)(out + orow + NV + col) = z;
    }
}

// ================= fallback (ws too small): proven R1 path =================
typedef float2 fl2;
__device__ __forceinline__ bf16x8 cvt8(f32x4 a, f32x4 b) {
    union { unsigned u[4]; bf16x8 v; } r;
    r.u[0] = pk2(a[0], a[1]); r.u[1] = pk2(a[2], a[3]);
    r.u[2] = pk2(b[0], b[1]); r.u[3] = pk2(b[2], b[3]);
    return r.v;
}
__device__ __forceinline__ void sload(const float*& bptr, fl2 (&r)[8]) {
    #pragma unroll
    for (int gi = 0; gi < 4; ++gi) {
        const float* p = bptr + (size_t)(gi * 32) * NV;
        r[2 * gi]     = *(const fl2*)(p);
        r[2 * gi + 1] = *(const fl2*)(p + NV);
    }
    bptr += (size_t)128 * NV;
}
__device__ __forceinline__ void wstage(unsigned char* buf, const fl2 (&r)[8],
                                       int kq, int nq, int sw0, int sw1) {
    #pragma unroll
    for (int gi = 0; gi < 4; ++gi) {
        unsigned lo = pk2(r[2 * gi].x, r[2 * gi + 1].x);
        unsigned hi = pk2(r[2 * gi].y, r[2 * gi + 1].y);
        const int kbyte = (kq + gi * 32) * 2;
        *(unsigned*)(buf + nq * 256       + (kbyte ^ sw0)) = lo;
        *(unsigned*)(buf + (nq + 1) * 256 + (kbyte ^ sw1)) = hi;
    }
}
__device__ __forceinline__ void compute_fb(const unsigned char* buf,
        const float* __restrict__ X, size_t arow0, size_t arow1,
        int ln, int lg, f32x4 (&acc)[2][2]) {
    bf16x8 afr[2][4];
    #pragma unroll
    for (int ks = 0; ks < 4; ++ks) {
        f32x4 p0 = *(const f32x4*)(X + arow0 + ks * 32);
        f32x4 p1 = *(const f32x4*)(X + arow0 + ks * 32 + 4);
        afr[0][ks] = cvt8(p0, p1);
        f32x4 q0 = *(const f32x4*)(X + arow1 + ks * 32);
        f32x4 q1 = *(const f32x4*)(X + arow1 + ks * 32 + 4);
        afr[1][ks] = cvt8(q0, q1);
    }
    const int swn = (ln & 7) << 4;
    #pragma unroll
    for (int nt = 0; nt < 2; ++nt) {
        const int rowb = (nt * 16 + ln) * 256;
        #pragma unroll
        for (int ks = 0; ks < 4; ++ks) {
            bf16x8 bfr = *(const bf16x8*)(buf + rowb + (((lg * 16) + ks * 64) ^ swn));
            acc[0][nt] = __builtin_amdgcn_mfma_f32_16x16x32_bf16(afr[0][ks], bfr, acc[0][nt], 0, 0, 0);
            acc[1][nt] = __builtin_amdgcn_mfma_f32_16x16x32_bf16(afr[1][ks], bfr, acc[1][nt], 0, 0, 0);
        }
    }
}
__global__ __launch_bounds__(256) void gemm_fb_kernel(const float* __restrict__ X,
        const float* __restrict__ R, float* __restrict__ out) {
    __shared__ unsigned char Bs0[32 * 256];
    __shared__ unsigned char Bs1[32 * 256];
    const int tid = threadIdx.x;
    const int w = tid >> 6, l = tid & 63;
    const int ln = l & 15, lg = l >> 4;
    const int chunk = blockIdx.x / 192;
    const int nb = blockIdx.x % 192;
    const int n0 = nb * 32;
    const int kbase = chunk * (NV / 2);
    const int nsi = (NV / 2) / 128;
    const int kq = (tid >> 4) * 2;
    const int nq = (tid & 15) * 2;
    const float* bptr = R + (size_t)(kbase + kq) * NV + (n0 + nq);
    const int sw0 = (nq & 7) << 4;
    const int sw1 = ((nq + 1) & 7) << 4;
    size_t arow0 = (size_t)(w * 32 + ln) * NPIX + kbase + lg * 8;
    size_t arow1 = arow0 + (size_t)16 * NPIX;
    f32x4 acc[2][2];
    #pragma unroll
    for (int a = 0; a < 2; ++a)
        #pragma unroll
        for (int b = 0; b < 2; ++b) {
            acc[a][b][0] = 0.f; acc[a][b][1] = 0.f;
            acc[a][b][2] = 0.f; acc[a][b][3] = 0.f;
        }
    fl2 ring0[8], ring1[8];
    sload(bptr, ring0);
    sload(bptr, ring1);
    wstage(Bs0, ring0, kq, nq, sw0, sw1);
    __syncthreads();
    #pragma unroll 1
    for (int it = 0; it < nsi / 2; ++it) {
        const int s = it * 2;
        if (s + 2 < nsi) sload(bptr, ring0);
        compute_fb(Bs0, X, arow0, arow1, ln, lg, acc);
        arow0 += 128; arow1 += 128;
        wstage(Bs1, ring1, kq, nq, sw0, sw1);
        __syncthreads();
        if (s + 3 < nsi) sload(bptr, ring1);
        compute_fb(Bs1, X, arow0, arow1, ln, lg, acc);
        arow0 += 128; arow1 += 128;
        if (s + 2 < nsi) wstage(Bs0, ring0, kq, nq, sw0, sw1);
        __syncthreads();
    }
    float* dst = out + (size_t)chunk * NV;
    #pragma unroll
    for (int mt = 0; mt < 2; ++mt) {
        const int mbase = w * 32 + mt * 16 + lg * 4;
        #pragma unroll
        for (int nt = 0; nt < 2; ++nt) {
            const size_t cb = (size_t)(n0 + nt * 16 + ln);
            #pragma unroll
            for (int j = 0; j < 4; ++j)
                dst[(size_t)(mbase + j) * NPIX + cb] = acc[mt][nt][j];
        }
    }
}
__global__ __launch_bounds__(256) void reduce_fb_kernel(float* __restrict__ out) {
    int q = blockIdx.x * 256 + threadIdx.x;
    int m = q / (NV / 4);
    int r = q % (NV / 4);
    size_t base = (size_t)m * NPIX + r * 4;
    f32x4 a = *(f32x4*)(out + base);
    f32x4 b = *(f32x4*)(out + base + NV);
    f32x4 cz, z;
    #pragma unroll
    for (int i = 0; i < 4; ++i) {
        float v = a[i] + b[i];
        cz[i] = fminf(fmaxf(v, 0.f), 1.f);
        z[i] = 0.f;
    }
    *(f32x4*)(out + base) = cz;
    *(f32x4*)(out + base + NV) = z;
}

extern "C" void kernel_launch(void* const* d_in, const int* in_sizes, int n_in,
                              void* d_out, int out_size, void* d_ws, size_t ws_size,
                              hipStream_t stream) {
    const float* x = (const float*)d_in[0];   // (8,16,12288) fp32
    const float* R = (const float*)d_in[1];   // (6144,6144) fp32
    float* out = (float*)d_out;               // (8,16,12288) fp32

    const size_t abytes = (size_t)MR * LDA * 2;          // 1.59 MB bf16 A
    const size_t pbytes = (size_t)CH * SLOTF * 4;        // 48 MB partials

    if (ws_size >= abytes + pbytes) {
        unsigned short* abf = (unsigned short*)d_ws;
        float* part = (float*)((char*)d_ws + abytes);
        prep_kernel<<<(MR * NV / 8) / 256, 256, 0, stream>>>(x, abf);
        gemm4_kernel<<<24 * CH, 512, 0, stream>>>(abf, R, part);
        reduce4_kernel<<<24 * 8, 256, 0, stream>>>(out, part);
    } else {
        gemm_fb_kernel<<<192 * 2, 256, 0, stream>>>(x, R, out);
        reduce_fb_kernel<<<(MR * NV / 4) / 256, 256, 0, stream>>>(out);
    }
}